// Round 4
// baseline (266.407 us; speedup 1.0000x reference)
//
#include <hip/hip_runtime.h>
#include <math.h>

#define NCLS 1000
#define MT 33
#define D 1024
#define BETA 5.5f

__device__ __forceinline__ float wave_sum(float v) {
#pragma unroll
  for (int off = 32; off; off >>= 1) v += __shfl_xor(v, off, 64);
  return v;
}

__device__ __forceinline__ float wave_max(float v) {
#pragma unroll
  for (int off = 32; off; off >>= 1) v = fmaxf(v, __shfl_xor(v, off, 64));
  return v;
}

__device__ __forceinline__ float dot4(float4 a, float4 b) {
  return a.x * b.x + a.y * b.y + a.z * b.z + a.w * b.w;
}

__global__ __launch_bounds__(1024) void zero_kernel(float* __restrict__ s,
                                                    unsigned* __restrict__ cnt) {
  s[threadIdx.x] = 0.0f;
  if (threadIdx.x == 0) *cnt = 0u;
}

// column sum of global_bias [NCLS, D] into s[D] (s pre-zeroed)
__global__ __launch_bounds__(1024) void colsum_kernel(const float* __restrict__ gb,
                                                      float* __restrict__ s) {
  const int t = threadIdx.x;
  float p = 0.0f;
  for (int c = blockIdx.x; c < NCLS; c += gridDim.x) p += gb[(size_t)c * D + t];
  atomicAdd(&s[t], p);
}

// 256 threads = 4 waves; each wave owns the full D=1024 dims in registers
// (lane l, chunk k -> dim k*256 + l*4 .. +3). One barrier in the main path.
// Last-arriving block runs the 1000-wide softmax inline (no separate dispatch).
__global__ __launch_bounds__(256, 4) void main_kernel(
    const float* __restrict__ memp, const float* __restrict__ gbk,
    const float* __restrict__ gbv, const float* __restrict__ gffn,
    const float* __restrict__ img, const float* __restrict__ s,
    const float* __restrict__ ls, float* __restrict__ logits,
    unsigned* __restrict__ cnt, float* __restrict__ out) {
  __shared__ float red[4][D];  // 16 KB cross-wave partials (reused as softmax scr)
  __shared__ int winner_flag;
  const int c = blockIdx.x;
  const int t = threadIdx.x;
  const int wv = t >> 6, lane = t & 63;
  const int dbase = lane * 4;

  const float* gbk_c = gbk + (size_t)c * D;
  const float* gbv_c = gbv + (size_t)c * D;

  // ---- q recomputed per wave ----
  float4 qv[4], kv[4], vvr[4];
  float qss = 0.0f;
#pragma unroll
  for (int k = 0; k < 4; ++k) {
    const int d = k * 256 + dbase;
    const float4 iv = *(const float4*)(img + d);
    const float4 sv = *(const float4*)(s + d);
    float4 v;
    v.x = iv.x + sv.x * (1.0f / (float)NCLS);
    v.y = iv.y + sv.y * (1.0f / (float)NCLS);
    v.z = iv.z + sv.z * (1.0f / (float)NCLS);
    v.w = iv.w + sv.w * (1.0f / (float)NCLS);
    qv[k] = v;
    qss += dot4(v, v);
    kv[k] = *(const float4*)(gbk_c + d);
    vvr[k] = *(const float4*)(gbv_c + d);
  }
  qss = wave_sum(qss);
  const float qinv = 1.0f / sqrtf(qss);
#pragma unroll
  for (int k = 0; k < 4; ++k) {
    qv[k].x *= qinv; qv[k].y *= qinv; qv[k].z *= qinv; qv[k].w *= qinv;
  }

  // per-class scalars: ||gbk||^2, ||gbv||^2, q.gbk (redundant per wave)
  float kk = 0.0f, vv2 = 0.0f, qk = 0.0f;
#pragma unroll
  for (int k = 0; k < 4; ++k) {
    kk += dot4(kv[k], kv[k]);
    vv2 += dot4(vvr[k], vvr[k]);
    qk += dot4(qv[k], kv[k]);
  }
  kk = wave_sum(kk);
  vv2 = wave_sum(vv2);
  qk = wave_sum(qk);

  float4 acc[4];
#pragma unroll
  for (int k = 0; k < 4; ++k) acc[k] = make_float4(0.f, 0.f, 0.f, 0.f);
  float Wsum = 0.0f;

  // ---- slot loop with 2-deep prefetch: wave wv handles slots wv, wv+4, ...
  const float* memc = memp + (size_t)c * MT * D;
  int m = wv;
  float4 mv[4];
  {
    const float* rp = memc + (size_t)m * D + dbase;
#pragma unroll
    for (int k = 0; k < 4; ++k) mv[k] = *(const float4*)(rp + k * 256);
  }
  while (m < MT) {
    const int mn = m + 4;
    float4 nx[4];
    if (mn < MT) {
      const float* np = memc + (size_t)mn * D + dbase;
#pragma unroll
      for (int k = 0; k < 4; ++k) nx[k] = *(const float4*)(np + k * 256);
    }
    float pqm = 0.f, pkm = 0.f, pvm = 0.f, pmm = 0.f;
#pragma unroll
    for (int k = 0; k < 4; ++k) {
      pqm += dot4(qv[k], mv[k]);
      pkm += dot4(kv[k], mv[k]);
      pvm += dot4(vvr[k], mv[k]);
      pmm += dot4(mv[k], mv[k]);
    }
    pqm = wave_sum(pqm);
    pkm = wave_sum(pkm);
    pvm = wave_sum(pvm);
    pmm = wave_sum(pmm);

    // empty row <=> all elements zero <=> sum of squares == 0
    const float nk = sqrtf(pmm + 2.0f * pkm + kk);
    const float cosv = (pqm + qk) / nk;
    const float sim = expf(-BETA * (1.0f - cosv));
    const float nv = sqrtf(pmm + 2.0f * pvm + vv2);
    const float wgt = (pmm == 0.0f) ? 0.0f : sim / nv;
    Wsum += wgt;
#pragma unroll
    for (int k = 0; k < 4; ++k) {
      acc[k].x += wgt * mv[k].x;
      acc[k].y += wgt * mv[k].y;
      acc[k].z += wgt * mv[k].z;
      acc[k].w += wgt * mv[k].w;
    }
#pragma unroll
    for (int k = 0; k < 4; ++k) mv[k] = nx[k];
    m = mn;
  }
  // fold (sum_m w_m) * gbv into each wave's partial (linear, sums correctly)
#pragma unroll
  for (int k = 0; k < 4; ++k) {
    acc[k].x += Wsum * vvr[k].x;
    acc[k].y += Wsum * vvr[k].y;
    acc[k].z += Wsum * vvr[k].z;
    acc[k].w += Wsum * vvr[k].w;
  }

  // ---- one-barrier cross-wave reduce; every wave gets full a_raw ----
#pragma unroll
  for (int k = 0; k < 4; ++k) *(float4*)(&red[wv][k * 256 + dbase]) = acc[k];
  __syncthreads();
#pragma unroll
  for (int k = 0; k < 4; ++k) {
    const float4 a0 = *(const float4*)(&red[0][k * 256 + dbase]);
    const float4 a1 = *(const float4*)(&red[1][k * 256 + dbase]);
    const float4 a2 = *(const float4*)(&red[2][k * 256 + dbase]);
    const float4 a3 = *(const float4*)(&red[3][k * 256 + dbase]);
    acc[k].x = a0.x + a1.x + a2.x + a3.x;
    acc[k].y = a0.y + a1.y + a2.y + a3.y;
    acc[k].z = a0.z + a1.z + a2.z + a3.z;
    acc[k].w = a0.w + a1.w + a2.w + a3.w;
  }

  // ---- stage 2, barrier-free (replicated per wave) ----
  float n1 = 0.0f;
#pragma unroll
  for (int k = 0; k < 4; ++k) n1 += dot4(acc[k], acc[k]);
  n1 = wave_sum(n1);
  const float inv1 = 1.0f / sqrtf(n1);

  const float* gffn_c = gffn + (size_t)c * D;
  float n2 = 0.0f, d3 = 0.0f;
#pragma unroll
  for (int k = 0; k < 4; ++k) {
    const int d = k * 256 + dbase;
    const float4 gf = *(const float4*)(gffn_c + d);
    const float4 iv = *(const float4*)(img + d);
    float4 a1v;
    a1v.x = acc[k].x * inv1 + gf.x;
    a1v.y = acc[k].y * inv1 + gf.y;
    a1v.z = acc[k].z * inv1 + gf.z;
    a1v.w = acc[k].w * inv1 + gf.w;
    n2 += dot4(a1v, a1v);
    d3 += dot4(a1v, iv);
  }
  n2 = wave_sum(n2);
  d3 = wave_sum(d3);

  // ---- completion ticket: last block runs softmax inline ----
  if (t == 0) {
    logits[c] = expf(ls[0]) * d3 / sqrtf(n2);
    __threadfence();  // release: make logit visible device-wide
    const unsigned old = atomicAdd(cnt, 1u);
    winner_flag = (old == NCLS - 1) ? 1 : 0;
  }
  __syncthreads();
  if (winner_flag) {
    __threadfence();  // acquire: see all other blocks' logits
    const int i4 = t * 4;  // NCLS==1000, threads 0..249 each own a full float4
    float4 lv = make_float4(-INFINITY, -INFINITY, -INFINITY, -INFINITY);
    if (i4 < NCLS) lv = *(const float4*)(logits + i4);
    float mloc = fmaxf(fmaxf(lv.x, lv.y), fmaxf(lv.z, lv.w));
    mloc = wave_max(mloc);
    if (lane == 0) red[0][wv] = mloc;
    __syncthreads();
    const float mall = fmaxf(fmaxf(red[0][0], red[0][1]), fmaxf(red[0][2], red[0][3]));
    float4 ev = make_float4(0.f, 0.f, 0.f, 0.f);
    if (i4 < NCLS) {
      ev.x = expf(lv.x - mall);
      ev.y = expf(lv.y - mall);
      ev.z = expf(lv.z - mall);
      ev.w = expf(lv.w - mall);
    }
    float sloc = wave_sum(ev.x + ev.y + ev.z + ev.w);
    if (lane == 0) red[1][wv] = sloc;
    __syncthreads();
    const float inv_s = 1.0f / (red[1][0] + red[1][1] + red[1][2] + red[1][3]);
    if (i4 < NCLS) {
      float4 o;
      o.x = ev.x * inv_s;
      o.y = ev.y * inv_s;
      o.z = ev.z * inv_s;
      o.w = ev.w * inv_s;
      *(float4*)(out + i4) = o;
    }
  }
}

extern "C" void kernel_launch(void* const* d_in, const int* in_sizes, int n_in,
                              void* d_out, int out_size, void* d_ws, size_t ws_size,
                              hipStream_t stream) {
  const float* img = (const float*)d_in[0];
  const float* memp = (const float*)d_in[1];
  const float* gb = (const float*)d_in[2];
  const float* gbk = (const float*)d_in[3];
  const float* gbv = (const float*)d_in[4];
  const float* gffn = (const float*)d_in[5];
  const float* ls = (const float*)d_in[6];
  float* out = (float*)d_out;

  float* s = (float*)d_ws;        // [D]
  float* logits = s + D;          // [NCLS] (padded to 1024)
  unsigned* cnt = (unsigned*)(s + 2 * D + 1024);  // aligned scalar counter

  zero_kernel<<<1, D, 0, stream>>>(s, cnt);
  colsum_kernel<<<64, D, 0, stream>>>(gb, s);
  main_kernel<<<NCLS, 256, 0, stream>>>(memp, gbk, gbv, gffn, img, s, ls, logits,
                                        cnt, out);
}

// Round 8
// 229.055 us; speedup vs baseline: 1.1631x; 1.1631x over previous
//
#include <hip/hip_runtime.h>
#include <math.h>

#define NCLS 1000
#define MT 33
#define D 1024
#define BETA 5.5f

__device__ __forceinline__ float wave_sum(float v) {
#pragma unroll
  for (int off = 32; off; off >>= 1) v += __shfl_xor(v, off, 64);
  return v;
}

__device__ __forceinline__ float dot4(float4 a, float4 b) {
  return a.x * b.x + a.y * b.y + a.z * b.z + a.w * b.w;
}

// block of 1024 threads (16 waves); scr must hold >=17 floats
__device__ __forceinline__ float block_sum16(float v, volatile float* scr) {
  v = wave_sum(v);
  const int wv = threadIdx.x >> 6, lane = threadIdx.x & 63;
  if (lane == 0) scr[wv] = v;
  __syncthreads();
  if (wv == 0) {
    float x = (lane < 16) ? scr[lane] : 0.0f;
#pragma unroll
    for (int off = 8; off; off >>= 1) x += __shfl_xor(x, off, 64);
    if (lane == 0) scr[16] = x;
  }
  __syncthreads();
  return scr[16];
}

__global__ __launch_bounds__(1024) void zero_kernel(float* __restrict__ s) {
  s[threadIdx.x] = 0.0f;
}

// column sum of global_bias [NCLS, D] into s[D] (s pre-zeroed)
__global__ __launch_bounds__(1024) void colsum_kernel(const float* __restrict__ gb,
                                                      float* __restrict__ s) {
  const int t = threadIdx.x;
  float p = 0.0f;
  for (int c = blockIdx.x; c < NCLS; c += gridDim.x) p += gb[(size_t)c * D + t];
  atomicAdd(&s[t], p);
}

// 256 threads = 4 waves; each wave owns the full D=1024 dims in registers
// (lane l, chunk k -> dim k*256 + l*4 .. +3). One barrier total.
// launch_bounds(256,2): 256-VGPR cap so q/k/v/acc stay register-resident
// (R4's (256,4) made the compiler pick 64 VGPRs and re-load operands in-loop
// -> latency-bound at 10% HBM peak).
__global__ __launch_bounds__(256, 2) void main_kernel(
    const float* __restrict__ memp, const float* __restrict__ gbk,
    const float* __restrict__ gbv, const float* __restrict__ gffn,
    const float* __restrict__ img, const float* __restrict__ s,
    const float* __restrict__ ls, float* __restrict__ logits) {
  __shared__ float red[4][D];  // 16 KB cross-wave partials
  const int c = blockIdx.x;
  const int t = threadIdx.x;
  const int wv = t >> 6, lane = t & 63;
  const int dbase = lane * 4;

  const float* gbk_c = gbk + (size_t)c * D;
  const float* gbv_c = gbv + (size_t)c * D;

  // ---- q recomputed per wave ----
  float4 qv[4], kv[4], vvr[4];
  float qss = 0.0f;
#pragma unroll
  for (int k = 0; k < 4; ++k) {
    const int d = k * 256 + dbase;
    const float4 iv = *(const float4*)(img + d);
    const float4 sv = *(const float4*)(s + d);
    float4 v;
    v.x = iv.x + sv.x * (1.0f / (float)NCLS);
    v.y = iv.y + sv.y * (1.0f / (float)NCLS);
    v.z = iv.z + sv.z * (1.0f / (float)NCLS);
    v.w = iv.w + sv.w * (1.0f / (float)NCLS);
    qv[k] = v;
    qss += dot4(v, v);
    kv[k] = *(const float4*)(gbk_c + d);
    vvr[k] = *(const float4*)(gbv_c + d);
  }
  qss = wave_sum(qss);
  const float qinv = 1.0f / sqrtf(qss);
#pragma unroll
  for (int k = 0; k < 4; ++k) {
    qv[k].x *= qinv; qv[k].y *= qinv; qv[k].z *= qinv; qv[k].w *= qinv;
  }

  // per-class scalars: ||gbk||^2, ||gbv||^2, q.gbk (redundant per wave)
  float kk = 0.0f, vv2 = 0.0f, qk = 0.0f;
#pragma unroll
  for (int k = 0; k < 4; ++k) {
    kk += dot4(kv[k], kv[k]);
    vv2 += dot4(vvr[k], vvr[k]);
    qk += dot4(qv[k], kv[k]);
  }
  kk = wave_sum(kk);
  vv2 = wave_sum(vv2);
  qk = wave_sum(qk);

  float4 acc[4];
#pragma unroll
  for (int k = 0; k < 4; ++k) acc[k] = make_float4(0.f, 0.f, 0.f, 0.f);
  float Wsum = 0.0f;

  // ---- slot loop: wave wv handles slots wv, wv+4, ... (8-9 iters) ----
  const float* memc = memp + (size_t)c * MT * D;
  for (int m = wv; m < MT; m += 4) {
    float4 mv[4];
#pragma unroll
    for (int k = 0; k < 4; ++k)
      mv[k] = *(const float4*)(memc + (size_t)m * D + k * 256 + dbase);
    float pqm = 0.f, pkm = 0.f, pvm = 0.f, pmm = 0.f;
#pragma unroll
    for (int k = 0; k < 4; ++k) {
      pqm += dot4(qv[k], mv[k]);
      pkm += dot4(kv[k], mv[k]);
      pvm += dot4(vvr[k], mv[k]);
      pmm += dot4(mv[k], mv[k]);
    }
    pqm = wave_sum(pqm);
    pkm = wave_sum(pkm);
    pvm = wave_sum(pvm);
    pmm = wave_sum(pmm);

    // empty row <=> all elements zero <=> sum of squares == 0
    const float nk = sqrtf(pmm + 2.0f * pkm + kk);
    const float cosv = (pqm + qk) / nk;
    const float sim = expf(-BETA * (1.0f - cosv));
    const float nv = sqrtf(pmm + 2.0f * pvm + vv2);
    const float wgt = (pmm == 0.0f) ? 0.0f : sim / nv;
    Wsum += wgt;
#pragma unroll
    for (int k = 0; k < 4; ++k) {
      acc[k].x += wgt * mv[k].x;
      acc[k].y += wgt * mv[k].y;
      acc[k].z += wgt * mv[k].z;
      acc[k].w += wgt * mv[k].w;
    }
  }
  // fold (sum_m w_m) * gbv into each wave's partial (linear, sums correctly)
#pragma unroll
  for (int k = 0; k < 4; ++k) {
    acc[k].x += Wsum * vvr[k].x;
    acc[k].y += Wsum * vvr[k].y;
    acc[k].z += Wsum * vvr[k].z;
    acc[k].w += Wsum * vvr[k].w;
  }

  // ---- one-barrier cross-wave reduce; every wave gets full a_raw ----
#pragma unroll
  for (int k = 0; k < 4; ++k) *(float4*)(&red[wv][k * 256 + dbase]) = acc[k];
  __syncthreads();
#pragma unroll
  for (int k = 0; k < 4; ++k) {
    const float4 a0 = *(const float4*)(&red[0][k * 256 + dbase]);
    const float4 a1 = *(const float4*)(&red[1][k * 256 + dbase]);
    const float4 a2 = *(const float4*)(&red[2][k * 256 + dbase]);
    const float4 a3 = *(const float4*)(&red[3][k * 256 + dbase]);
    acc[k].x = a0.x + a1.x + a2.x + a3.x;
    acc[k].y = a0.y + a1.y + a2.y + a3.y;
    acc[k].z = a0.z + a1.z + a2.z + a3.z;
    acc[k].w = a0.w + a1.w + a2.w + a3.w;
  }

  // ---- stage 2, barrier-free (replicated per wave) ----
  float n1 = 0.0f;
#pragma unroll
  for (int k = 0; k < 4; ++k) n1 += dot4(acc[k], acc[k]);
  n1 = wave_sum(n1);
  const float inv1 = 1.0f / sqrtf(n1);

  const float* gffn_c = gffn + (size_t)c * D;
  float n2 = 0.0f, d3 = 0.0f;
#pragma unroll
  for (int k = 0; k < 4; ++k) {
    const int d = k * 256 + dbase;
    const float4 gf = *(const float4*)(gffn_c + d);
    const float4 iv = *(const float4*)(img + d);
    float4 a1v;
    a1v.x = acc[k].x * inv1 + gf.x;
    a1v.y = acc[k].y * inv1 + gf.y;
    a1v.z = acc[k].z * inv1 + gf.z;
    a1v.w = acc[k].w * inv1 + gf.w;
    n2 += dot4(a1v, a1v);
    d3 += dot4(a1v, iv);
  }
  n2 = wave_sum(n2);
  d3 = wave_sum(d3);
  if (t == 0) logits[c] = expf(ls[0]) * d3 / sqrtf(n2);
}

__global__ __launch_bounds__(1024) void softmax_kernel(const float* __restrict__ logits,
                                                       float* __restrict__ out) {
  __shared__ float scr[40];
  const int t = threadIdx.x;
  const int wv = t >> 6, lane = t & 63;
  const float l = (t < NCLS) ? logits[t] : -INFINITY;
  float m = l;
#pragma unroll
  for (int off = 32; off; off >>= 1) m = fmaxf(m, __shfl_xor(m, off, 64));
  if (lane == 0) scr[wv] = m;
  __syncthreads();
  if (wv == 0) {
    float x = (lane < 16) ? scr[lane] : -INFINITY;
#pragma unroll
    for (int off = 8; off; off >>= 1) x = fmaxf(x, __shfl_xor(x, off, 64));
    if (lane == 0) scr[16] = x;
  }
  __syncthreads();
  m = scr[16];
  const float e = (t < NCLS) ? expf(l - m) : 0.0f;
  const float sden = block_sum16(e, scr);
  if (t < NCLS) out[t] = e / sden;
}

extern "C" void kernel_launch(void* const* d_in, const int* in_sizes, int n_in,
                              void* d_out, int out_size, void* d_ws, size_t ws_size,
                              hipStream_t stream) {
  const float* img = (const float*)d_in[0];
  const float* memp = (const float*)d_in[1];
  const float* gb = (const float*)d_in[2];
  const float* gbk = (const float*)d_in[3];
  const float* gbv = (const float*)d_in[4];
  const float* gffn = (const float*)d_in[5];
  const float* ls = (const float*)d_in[6];
  float* out = (float*)d_out;

  float* s = (float*)d_ws;  // [D]
  float* logits = s + D;    // [NCLS]

  zero_kernel<<<1, D, 0, stream>>>(s);
  colsum_kernel<<<64, D, 0, stream>>>(gb, s);
  main_kernel<<<NCLS, 256, 0, stream>>>(memp, gbk, gbv, gffn, img, s, ls, logits);
  softmax_kernel<<<1, D, 0, stream>>>(logits, out);
}